// Round 4
// baseline (460.842 us; speedup 1.0000x reference)
//
#include <hip/hip_runtime.h>

#define N_NODES 50000
#define N_RELSR 20
#define R_TOT   41          // 2*N_RELSR + 1
#define N_EDGES 500000
#define EMB     16
#define NCLS    16
#define NB      40
#define E_TOT   (2 * N_EDGES + N_NODES)   // 1,050,000
#define NE_COL  (N_NODES * EMB)           // 800,000
#define NBLK_N  ((N_NODES + 255) / 256)   // 196

// f32 -> bf16 round-to-nearest-even (manual, no header dependency)
__device__ __forceinline__ unsigned short f2bf(float f) {
    unsigned u = __float_as_uint(f);
    u += 0x7FFFu + ((u >> 16) & 1u);
    return (unsigned short)(u >> 16);
}

// decode enriched edge i -> (s, o, r)
__device__ __forceinline__ void edge_decode(int i, const int* __restrict__ src,
                                            const int* __restrict__ dst,
                                            const int* __restrict__ rel,
                                            int& s, int& o, int& r) {
    if (i < N_EDGES) {
        s = src[i]; o = dst[i]; r = rel[i];
    } else if (i < 2 * N_EDGES) {
        int j = i - N_EDGES;
        s = dst[j]; o = src[j]; r = rel[j] + N_RELSR;
    } else {
        int n = i - 2 * N_EDGES;
        s = n; o = n; r = 2 * N_RELSR;
    }
}

// cnt2[idx] = { count, local r-prefix within node s }

// ---- K1: segment counts; also record each edge's rank within its segment ---
__global__ void k_count(const int* __restrict__ src, const int* __restrict__ dst,
                        const int* __restrict__ rel, int2* __restrict__ cnt2,
                        int* __restrict__ rank) {
    int i = blockIdx.x * blockDim.x + threadIdx.x;
    if (i >= E_TOT) return;
    int s, o, r;
    edge_decode(i, src, dst, rel, s, o, r);
    rank[i] = atomicAdd(&cnt2[r * N_NODES + s].x, 1);
}

// ---- K2a: deg[s] = sum_r cnt[r,s]; local r-prefix into .y; per-block sums ---
__global__ void k_degA(int2* __restrict__ cnt2, int* __restrict__ deg,
                       int* __restrict__ bsum) {
    __shared__ int red[256];
    int t = threadIdx.x;
    int s = blockIdx.x * 256 + t;
    int run = 0;
    if (s < N_NODES) {
        for (int r = 0; r < R_TOT; r++) {
            int idx = r * N_NODES + s;
            int2 val = cnt2[idx];
            val.y = run;              // local exclusive prefix over r
            cnt2[idx] = val;
            run += val.x;
        }
        deg[s] = run;
    }
    red[t] = run;
    __syncthreads();
    for (int st = 128; st > 0; st >>= 1) {
        if (t < st) red[t] += red[t + st];
        __syncthreads();
    }
    if (t == 0) bsum[blockIdx.x] = red[0];
}

// ---- K2b: exclusive scan of 196 block sums (single tiny block) --------------
__global__ void k_degB(int* __restrict__ bsum) {
    __shared__ int sh[256];
    int t = threadIdx.x;
    int v = (t < NBLK_N) ? bsum[t] : 0;
    sh[t] = v;
    __syncthreads();
    for (int d = 1; d < 256; d <<= 1) {
        int x = (t >= d) ? sh[t - d] : 0;
        __syncthreads();
        sh[t] += x;
        __syncthreads();
    }
    if (t < NBLK_N) bsum[t] = sh[t] - v;   // exclusive
}

// ---- K2c: block-local scan of deg -> off (global CSR offsets) ---------------
__global__ void k_degC(const int* __restrict__ deg, const int* __restrict__ bsum,
                       int* __restrict__ off) {
    __shared__ int sh[256];
    int t = threadIdx.x;
    int s = blockIdx.x * 256 + t;
    int d = (s < N_NODES) ? deg[s] : 0;
    sh[t] = d;
    __syncthreads();
    for (int dd = 1; dd < 256; dd <<= 1) {
        int x = (t >= dd) ? sh[t - dd] : 0;
        __syncthreads();
        sh[t] += x;
        __syncthreads();
    }
    int excl = sh[t] - d + bsum[blockIdx.x];
    if (s < N_NODES) off[s] = excl;
    if (s == 0) off[N_NODES] = E_TOT;
}

// ---- K3: fill CSR records {(r<<16)|o, v} sorted by (s, r); no atomics -------
__global__ void k_fill(const int* __restrict__ src, const int* __restrict__ dst,
                       const int* __restrict__ rel, const int2* __restrict__ cnt2,
                       const int* __restrict__ rank, const int* __restrict__ off,
                       int2* __restrict__ recs) {
    int i = blockIdx.x * blockDim.x + threadIdx.x;
    if (i >= E_TOT) return;
    int s, o, r;
    edge_decode(i, src, dst, rel, s, o, r);
    int2 cr = cnt2[r * N_NODES + s];
    float v = 1.0f / (float)cr.x;
    recs[off[s] + cr.y + rank[i]] = make_int2((r << 16) | o, __float_as_int(v));
}

// ---- K4: w1[r,n,e] = sum_b comps1[r,b] * bases1[b,n,e]  -> bf16 -------------
// Round-4 (this session): MFMA. This is a [41x40]@[40x800000] GEMM; two
// source-level VALU forms both lost to the compiler (r-outer reclustering:
// 90-108us cache-BW bound; hoist: spilled, 335us). v_mfma_f32_16x16x32_f16
// makes the FLOPs free (~1us) so the kernel sits at its memory floor
// (read 128MB + write 65.6MB ~= 31us). f16 inputs (rel err 2^-12, values
// <=0.25) keep added error ~1e-5, far under the passing absmax 2.4e-4.
// f32 accumulate in MFMA; w1 stays bf16 so K6/K7 are unchanged.
// Layouts: D col=lane&15 (t), row=(lane>>4)*4+reg (r) [m89-verified].
// A[row=lane&15][k=(lane>>4)*8+j]; B[k=(lane>>4)*8+j][col=lane&15]; any
// consistent k-permutation between A and B cancels in the dot product.
typedef _Float16 f16x8 __attribute__((ext_vector_type(8)));
typedef float f32x4 __attribute__((ext_vector_type(4)));
#define CA_LD 65   // LDS leading-dim pad (bank spread)

__global__ void __launch_bounds__(256)
k_w1(const float* __restrict__ comps1, const float* __restrict__ bases1,
     unsigned short* __restrict__ w1) {
    __shared__ _Float16 ca[48 * CA_LD];
    int tid = threadIdx.x;
    for (int q = tid; q < 48 * 64; q += 256) {
        int row = q >> 6, k = q & 63;
        float v = (row < R_TOT && k < NB) ? comps1[row * NB + k] : 0.f;
        ca[row * CA_LD + k] = (_Float16)v;
    }
    __syncthreads();
    int lane = tid & 63, wave = tid >> 6;
    int c0 = lane & 15;          // col-sub (t) / A-row (r)
    int g  = lane >> 4;          // k-group
    // A fragments: [m-tile 0..2][k-chunk 0..1] -> rows m*16+c0, k = q*32+g*8+j
    f16x8 af[3][2];
#pragma unroll
    for (int m = 0; m < 3; m++)
#pragma unroll
        for (int q = 0; q < 2; q++)
#pragma unroll
            for (int j = 0; j < 8; j++)
                af[m][q][j] = ca[(m * 16 + c0) * CA_LD + q * 32 + g * 8 + j];

    size_t wbase = (size_t)blockIdx.x * 256 + (size_t)wave * 64;
#pragma unroll 1
    for (int it = 0; it < 4; it++) {
        int col = (int)wbase + it * 16 + c0;
        f16x8 b0, b1;
#pragma unroll
        for (int j = 0; j < 8; j++) {
            int k = g * 8 + j;                       // 0..31, all valid
            b0[j] = (_Float16)bases1[(size_t)k * NE_COL + col];
        }
#pragma unroll
        for (int j = 0; j < 8; j++) {
            int k = 32 + g * 8 + j;                  // valid only k<40 (g==0)
            b1[j] = (k < NB) ? (_Float16)bases1[(size_t)k * NE_COL + col]
                             : (_Float16)0.f;
        }
        f32x4 d0 = {0.f, 0.f, 0.f, 0.f};
        f32x4 d1 = {0.f, 0.f, 0.f, 0.f};
        f32x4 d2 = {0.f, 0.f, 0.f, 0.f};
        d0 = __builtin_amdgcn_mfma_f32_16x16x32_f16(af[0][0], b0, d0, 0, 0, 0);
        d0 = __builtin_amdgcn_mfma_f32_16x16x32_f16(af[0][1], b1, d0, 0, 0, 0);
        d1 = __builtin_amdgcn_mfma_f32_16x16x32_f16(af[1][0], b0, d1, 0, 0, 0);
        d1 = __builtin_amdgcn_mfma_f32_16x16x32_f16(af[1][1], b1, d1, 0, 0, 0);
        d2 = __builtin_amdgcn_mfma_f32_16x16x32_f16(af[2][0], b0, d2, 0, 0, 0);
        d2 = __builtin_amdgcn_mfma_f32_16x16x32_f16(af[2][1], b1, d2, 0, 0, 0);
#pragma unroll
        for (int i = 0; i < 4; i++) {                // rows 0..15
            int row = g * 4 + i;
            w1[(size_t)row * NE_COL + col] = f2bf(d0[i]);
        }
#pragma unroll
        for (int i = 0; i < 4; i++) {                // rows 16..31
            int row = 16 + g * 4 + i;
            w1[(size_t)row * NE_COL + col] = f2bf(d1[i]);
        }
#pragma unroll
        for (int i = 0; i < 4; i++) {                // rows 32..40 (predicated)
            int row = 32 + g * 4 + i;
            if (row < R_TOT)
                w1[(size_t)row * NE_COL + col] = f2bf(d2[i]);
        }
    }
}

// ---- K5: w2p[r,c,ep] = packed bf16 pair (e=2ep, 2ep+1) of ---------------------
//          sum_b comps2[r,b] * bases2[b,e,c]
__global__ void k_w2(const float* __restrict__ comps2, const float* __restrict__ bases2,
                     unsigned* __restrict__ w2p) {
    int r = blockIdx.x;        // 41 blocks
    int t = threadIdx.x;       // 128 = NCLS*EMB/2, t = c*8+ep
    int c = t >> 3, ep = t & 7;
    int e0 = 2 * ep, e1 = 2 * ep + 1;
    float a0 = 0.f, a1 = 0.f;
#pragma unroll 8
    for (int b = 0; b < NB; b++) {
        float cc = comps2[r * NB + b];
        a0 = fmaf(cc, bases2[b * (EMB * NCLS) + e0 * NCLS + c], a0);
        a1 = fmaf(cc, bases2[b * (EMB * NCLS) + e1 * NCLS + c], a1);
    }
    w2p[r * 128 + t] = ((unsigned)f2bf(a1) << 16) | (unsigned)f2bf(a0);
}

// ---- K6: layer-1 gather, 8 lanes/edge, 8-edge unroll ------------------------
__global__ void k_l1_gather(const int* __restrict__ off, const int2* __restrict__ recs,
                            const unsigned* __restrict__ w1p,
                            const float* __restrict__ bias1, float* __restrict__ h) {
    int t = blockIdx.x * blockDim.x + threadIdx.x;     // N_NODES*8
    if (t >= N_NODES * 8) return;
    int s = t >> 3, e2 = t & 7;
    int beg = off[s], end = off[s + 1];
    float ax = 0.f, ay = 0.f;
    int j = beg;
    for (; j + 7 < end; j += 8) {
        int2 rc[8];
        unsigned p[8];
#pragma unroll
        for (int k = 0; k < 8; k++) rc[k] = recs[j + k];
#pragma unroll
        for (int k = 0; k < 8; k++)
            p[k] = w1p[(size_t)(rc[k].x >> 16) * (NE_COL / 2) + (rc[k].x & 0xFFFF) * 8 + e2];
#pragma unroll
        for (int k = 0; k < 8; k++) {
            float v = __int_as_float(rc[k].y);
            ax = fmaf(v, __uint_as_float(p[k] << 16), ax);
            ay = fmaf(v, __uint_as_float(p[k] & 0xFFFF0000u), ay);
        }
    }
    for (; j < end; j++) {
        int2 rc = recs[j];
        unsigned p = w1p[(size_t)(rc.x >> 16) * (NE_COL / 2) + (rc.x & 0xFFFF) * 8 + e2];
        float v = __int_as_float(rc.y);
        ax = fmaf(v, __uint_as_float(p << 16), ax);
        ay = fmaf(v, __uint_as_float(p & 0xFFFF0000u), ay);
    }
    float2 res;
    res.x = fmaxf(ax + bias1[2 * e2], 0.f);
    res.y = fmaxf(ay + bias1[2 * e2 + 1], 0.f);
    ((float2*)h)[t] = res;
}

// ---- K6-alt (fallback if ws too small for w1): on-the-fly basis contraction -
__global__ void k_l1_gather_fly(const int* __restrict__ off, const int2* __restrict__ recs,
                                const float* __restrict__ comps1,
                                const float* __restrict__ bases1,
                                const float* __restrict__ bias1, float* __restrict__ h) {
    __shared__ float c1[R_TOT * NB];
    for (int q = threadIdx.x; q < R_TOT * NB; q += blockDim.x) c1[q] = comps1[q];
    __syncthreads();
    int t = blockIdx.x * blockDim.x + threadIdx.x;
    int s = t >> 4, e = t & 15;
    int beg = off[s], end = off[s + 1];
    float acc = 0.f;
    for (int j = beg; j < end; j++) {
        int2 rec = recs[j];
        int o = rec.x & 0xFFFF, r = rec.x >> 16;
        float v = __int_as_float(rec.y);
        const float* cr = &c1[r * NB];
        float w = 0.f;
#pragma unroll 8
        for (int b = 0; b < NB; b++) w += cr[b] * bases1[(size_t)b * NE_COL + o * EMB + e];
        acc += v * w;
    }
    h[t] = fmaxf(acc + bias1[e], 0.f);
}

// ---- K7: layer-2 gather, bf16 w2 in LDS -------------------------------------
// All 16 lanes of an edge-group load the same 64B h[o,:] row (L1 broadcast).
// w2 stored as packed bf16 pairs: [r][c][ep], c-stride 10 uints (lane-c bank
// pattern c*10%32 covers all 16 banks), r-stride 164 uints. 26,896 B LDS ->
// 4 blocks of 512 per CU (~100% occupancy vs 47% with the 53KB f32 tile).
#define W2C2 10
#define W2R2 (16 * W2C2 + 4)    // 164 uints per relation
__device__ __forceinline__ float l2_edge(int2 ra, const float* __restrict__ h,
                                         const unsigned* w2s, int cbase) {
    const float4* ha = (const float4*)(h + (size_t)(ra.x & 0xFFFF) * EMB);
    const unsigned* base = &w2s[(ra.x >> 16) * W2R2 + cbase];
    float4 h0 = ha[0], h1 = ha[1], h2 = ha[2], h3 = ha[3];
    uint2 q0 = *(const uint2*)(base + 0);
    uint2 q1 = *(const uint2*)(base + 2);
    uint2 q2 = *(const uint2*)(base + 4);
    uint2 q3 = *(const uint2*)(base + 6);
    float da;
    da  = h0.x * __uint_as_float(q0.x << 16);
    da = fmaf(h0.y, __uint_as_float(q0.x & 0xFFFF0000u), da);
    da = fmaf(h0.z, __uint_as_float(q0.y << 16), da);
    da = fmaf(h0.w, __uint_as_float(q0.y & 0xFFFF0000u), da);
    da = fmaf(h1.x, __uint_as_float(q1.x << 16), da);
    da = fmaf(h1.y, __uint_as_float(q1.x & 0xFFFF0000u), da);
    da = fmaf(h1.z, __uint_as_float(q1.y << 16), da);
    da = fmaf(h1.w, __uint_as_float(q1.y & 0xFFFF0000u), da);
    da = fmaf(h2.x, __uint_as_float(q2.x << 16), da);
    da = fmaf(h2.y, __uint_as_float(q2.x & 0xFFFF0000u), da);
    da = fmaf(h2.z, __uint_as_float(q2.y << 16), da);
    da = fmaf(h2.w, __uint_as_float(q2.y & 0xFFFF0000u), da);
    da = fmaf(h3.x, __uint_as_float(q3.x << 16), da);
    da = fmaf(h3.y, __uint_as_float(q3.x & 0xFFFF0000u), da);
    da = fmaf(h3.z, __uint_as_float(q3.y << 16), da);
    da = fmaf(h3.w, __uint_as_float(q3.y & 0xFFFF0000u), da);
    return __int_as_float(ra.y) * da;
}

__global__ void k_l2_gather(const int* __restrict__ off, const int2* __restrict__ recs,
                            const float* __restrict__ h, const unsigned* __restrict__ w2p,
                            const float* __restrict__ bias2, float* __restrict__ out) {
    __shared__ __align__(16) unsigned w2s[R_TOT * W2R2];   // 26,896 B
    for (int q = threadIdx.x; q < R_TOT * 128; q += blockDim.x) {
        int r = q >> 7;
        int x = q & 127;
        int c = x >> 3, ep = x & 7;
        w2s[r * W2R2 + c * W2C2 + ep] = w2p[q];
    }
    __syncthreads();
    int t = blockIdx.x * blockDim.x + threadIdx.x;
    if (t >= NE_COL) return;
    int s = t >> 4, c = t & 15;
    int beg = off[s], end = off[s + 1];
    int cbase = c * W2C2;
    float acc = 0.f;
    int j = beg;
    for (; j + 3 < end; j += 4) {
        int2 r0 = recs[j], r1 = recs[j + 1], r2 = recs[j + 2], r3 = recs[j + 3];
        float t0 = l2_edge(r0, h, w2s, cbase);
        float t1 = l2_edge(r1, h, w2s, cbase);
        float t2 = l2_edge(r2, h, w2s, cbase);
        float t3 = l2_edge(r3, h, w2s, cbase);
        acc += (t0 + t1) + (t2 + t3);
    }
    for (; j < end; j++) {
        acc += l2_edge(recs[j], h, w2s, cbase);
    }
    out[s * NCLS + c] = acc + bias2[c];
}

static inline size_t align64(size_t x) { return (x + 63) & ~(size_t)63; }

extern "C" void kernel_launch(void* const* d_in, const int* in_sizes, int n_in,
                              void* d_out, int out_size, void* d_ws, size_t ws_size,
                              hipStream_t stream) {
    const int*   src    = (const int*)d_in[0];
    const int*   dst    = (const int*)d_in[1];
    const int*   rel    = (const int*)d_in[2];
    const float* comps1 = (const float*)d_in[3];
    const float* bases1 = (const float*)d_in[4];
    const float* comps2 = (const float*)d_in[5];
    const float* bases2 = (const float*)d_in[6];
    const float* bias1  = (const float*)d_in[7];
    const float* bias2  = (const float*)d_in[8];
    float* out = (float*)d_out;
    (void)in_sizes; (void)n_in; (void)out_size;

    char* ws = (char*)d_ws;
    size_t off_b = 0;
    // w1 (bf16, 65.6 MB) first; cnt2 (16.4MB) + rank (4.2MB) alias its head
    // (both dead before k_w1 writes w1).
    unsigned short* w1 = (unsigned short*)ws;
    int2*  cnt2 = (int2*)ws;
    int*   rank = (int*)(ws + align64((size_t)R_TOT * N_NODES * 8));
    off_b = align64((size_t)R_TOT * NE_COL * 2);              // 65.6 MB
    int*      deg  = (int*)(ws + off_b);      off_b = align64(off_b + (size_t)N_NODES * 4);
    int*      off  = (int*)(ws + off_b);      off_b = align64(off_b + (size_t)(N_NODES + 1) * 4);
    int*      bsum = (int*)(ws + off_b);      off_b = align64(off_b + (size_t)256 * 4);
    int2*     recs = (int2*)(ws + off_b);     off_b = align64(off_b + (size_t)E_TOT * 8);
    float*    h    = (float*)(ws + off_b);    off_b = align64(off_b + (size_t)NE_COL * 4);
    unsigned* w2p  = (unsigned*)(ws + off_b); off_b = align64(off_b + (size_t)R_TOT * 128 * 4);
    const bool materialize_w1 = (ws_size >= off_b);
    if (!materialize_w1) {
        off_b = 0;
        cnt2 = (int2*)(ws + off_b);     off_b = align64(off_b + (size_t)R_TOT * N_NODES * 8);
        rank = (int*)(ws + off_b);      off_b = align64(off_b + (size_t)E_TOT * 4);
        deg  = (int*)(ws + off_b);      off_b = align64(off_b + (size_t)N_NODES * 4);
        off  = (int*)(ws + off_b);      off_b = align64(off_b + (size_t)(N_NODES + 1) * 4);
        bsum = (int*)(ws + off_b);      off_b = align64(off_b + (size_t)256 * 4);
        recs = (int2*)(ws + off_b);     off_b = align64(off_b + (size_t)E_TOT * 8);
        h    = (float*)(ws + off_b);    off_b = align64(off_b + (size_t)NE_COL * 4);
        w2p  = (unsigned*)(ws + off_b); off_b = align64(off_b + (size_t)R_TOT * 128 * 4);
    }

    // zero counts (.x of cnt2; .y overwritten by k_degA)
    hipMemsetAsync(cnt2, 0, (size_t)R_TOT * N_NODES * 8, stream);

    const int BLK = 256;
    const int g_edge = (E_TOT + BLK - 1) / BLK;           // 4102
    const int g_w1   = NE_COL / 256;                      // 3125 (exact)
    const int g_l1   = (N_NODES * 8 + BLK - 1) / BLK;     // 1563
    const int g_l1f  = (N_NODES * 16) / BLK;              // 3125 (fallback, 16-lane)
    const int g_l2   = (NE_COL + 511) / 512;              // 1563

    k_count<<<g_edge, BLK, 0, stream>>>(src, dst, rel, cnt2, rank);
    k_degA<<<NBLK_N, 256, 0, stream>>>(cnt2, deg, bsum);
    k_degB<<<1, 256, 0, stream>>>(bsum);
    k_degC<<<NBLK_N, 256, 0, stream>>>(deg, bsum, off);
    k_fill<<<g_edge, BLK, 0, stream>>>(src, dst, rel, cnt2, rank, off, recs);
    k_w2<<<R_TOT, 128, 0, stream>>>(comps2, bases2, w2p);

    if (materialize_w1) {
        k_w1<<<g_w1, 256, 0, stream>>>(comps1, bases1, w1);  // overwrites cnt2/rank (dead)
        k_l1_gather<<<g_l1, BLK, 0, stream>>>(off, recs, (const unsigned*)w1, bias1, h);
    } else {
        k_l1_gather_fly<<<g_l1f, BLK, 0, stream>>>(off, recs, comps1, bases1, bias1, h);
    }

    k_l2_gather<<<g_l2, 512, 0, stream>>>(off, recs, h, w2p, bias2, out);
}

// Round 5
// 404.988 us; speedup vs baseline: 1.1379x; 1.1379x over previous
//
#include <hip/hip_runtime.h>

#define N_NODES 50000
#define N_RELSR 20
#define R_TOT   41          // 2*N_RELSR + 1
#define N_EDGES 500000
#define EMB     16
#define NCLS    16
#define NB      40
#define E_TOT   (2 * N_EDGES + N_NODES)   // 1,050,000
#define NE_COL  (N_NODES * EMB)           // 800,000
#define NBLK_N  ((N_NODES + 255) / 256)   // 196

// f32 -> bf16 round-to-nearest-even (manual, no header dependency)
__device__ __forceinline__ unsigned short f2bf(float f) {
    unsigned u = __float_as_uint(f);
    u += 0x7FFFu + ((u >> 16) & 1u);
    return (unsigned short)(u >> 16);
}

// decode enriched edge i -> (s, o, r)
__device__ __forceinline__ void edge_decode(int i, const int* __restrict__ src,
                                            const int* __restrict__ dst,
                                            const int* __restrict__ rel,
                                            int& s, int& o, int& r) {
    if (i < N_EDGES) {
        s = src[i]; o = dst[i]; r = rel[i];
    } else if (i < 2 * N_EDGES) {
        int j = i - N_EDGES;
        s = dst[j]; o = src[j]; r = rel[j] + N_RELSR;
    } else {
        int n = i - 2 * N_EDGES;
        s = n; o = n; r = 2 * N_RELSR;
    }
}

// cnt2[idx] = { count, local r-prefix within node s }

// ---- K1: segment counts; also record each edge's rank within its segment ---
__global__ void k_count(const int* __restrict__ src, const int* __restrict__ dst,
                        const int* __restrict__ rel, int2* __restrict__ cnt2,
                        int* __restrict__ rank) {
    int i = blockIdx.x * blockDim.x + threadIdx.x;
    if (i >= E_TOT) return;
    int s, o, r;
    edge_decode(i, src, dst, rel, s, o, r);
    rank[i] = atomicAdd(&cnt2[r * N_NODES + s].x, 1);
}

// ---- K2a: deg[s] = sum_r cnt[r,s]; local r-prefix into .y; per-block sums ---
__global__ void k_degA(int2* __restrict__ cnt2, int* __restrict__ deg,
                       int* __restrict__ bsum) {
    __shared__ int red[256];
    int t = threadIdx.x;
    int s = blockIdx.x * 256 + t;
    int run = 0;
    if (s < N_NODES) {
        for (int r = 0; r < R_TOT; r++) {
            int idx = r * N_NODES + s;
            int2 val = cnt2[idx];
            val.y = run;              // local exclusive prefix over r
            cnt2[idx] = val;
            run += val.x;
        }
        deg[s] = run;
    }
    red[t] = run;
    __syncthreads();
    for (int st = 128; st > 0; st >>= 1) {
        if (t < st) red[t] += red[t + st];
        __syncthreads();
    }
    if (t == 0) bsum[blockIdx.x] = red[0];
}

// ---- K2b: exclusive scan of 196 block sums (single tiny block) --------------
__global__ void k_degB(int* __restrict__ bsum) {
    __shared__ int sh[256];
    int t = threadIdx.x;
    int v = (t < NBLK_N) ? bsum[t] : 0;
    sh[t] = v;
    __syncthreads();
    for (int d = 1; d < 256; d <<= 1) {
        int x = (t >= d) ? sh[t - d] : 0;
        __syncthreads();
        sh[t] += x;
        __syncthreads();
    }
    if (t < NBLK_N) bsum[t] = sh[t] - v;   // exclusive
}

// ---- K2c: block-local scan of deg -> off (global CSR offsets) ---------------
__global__ void k_degC(const int* __restrict__ deg, const int* __restrict__ bsum,
                       int* __restrict__ off) {
    __shared__ int sh[256];
    int t = threadIdx.x;
    int s = blockIdx.x * 256 + t;
    int d = (s < N_NODES) ? deg[s] : 0;
    sh[t] = d;
    __syncthreads();
    for (int dd = 1; dd < 256; dd <<= 1) {
        int x = (t >= dd) ? sh[t - dd] : 0;
        __syncthreads();
        sh[t] += x;
        __syncthreads();
    }
    int excl = sh[t] - d + bsum[blockIdx.x];
    if (s < N_NODES) off[s] = excl;
    if (s == 0) off[N_NODES] = E_TOT;
}

// ---- K3: fill CSR records {(r<<16)|o, v} sorted by (s, r); no atomics -------
__global__ void k_fill(const int* __restrict__ src, const int* __restrict__ dst,
                       const int* __restrict__ rel, const int2* __restrict__ cnt2,
                       const int* __restrict__ rank, const int* __restrict__ off,
                       int2* __restrict__ recs) {
    int i = blockIdx.x * blockDim.x + threadIdx.x;
    if (i >= E_TOT) return;
    int s, o, r;
    edge_decode(i, src, dst, rel, s, o, r);
    int2 cr = cnt2[r * N_NODES + s];
    float v = 1.0f / (float)cr.x;
    recs[off[s] + cr.y + rank[i]] = make_int2((r << 16) | o, __float_as_int(v));
}

// ---- K4: w1[r,n,e] = sum_b comps1[r,b] * bases1[b,n,e]  -> bf16 -------------
// Round-5 (this session): MFMA + LDS-staged B. Round-4's MFMA was correct
// (absmax unchanged) but latency-bound at 122us: 16 scalar 4B B-loads per
// it with no cross-it overlap (VALU 10%, Mfma 1.5%, HBM 19% - all idle).
// Fix: stage the 40x256 f32 bases1 tile via coalesced float2 loads into a
// swizzled f16 LDS tile, so each B fragment is ONE aligned ds_read_b128.
//   physical f16 idx = col*64 + ((kb ^ ((col>>1)&7))<<3) + ko   (kb=k/8,ko=k&7)
// Write+read use the same involution => self-consistent (bug -> absmax blow).
// Reads ~2-way conflict (free); writes ~8-way on 40 cheap u16s, once/block.
// f32 accumulate in MFMA; w1 stays bf16 so K6/K7 are unchanged.
// D layout col=lane&15, row=(lane>>4)*4+reg [m89-verified, proven round-4].
typedef _Float16 f16x8 __attribute__((ext_vector_type(8)));
typedef float f32x4 __attribute__((ext_vector_type(4)));
#define CA_LD 65   // LDS leading-dim pad (bank spread)

__global__ void __launch_bounds__(256)
k_w1(const float* __restrict__ comps1, const float* __restrict__ bases1,
     unsigned short* __restrict__ w1) {
    __shared__ _Float16 ca[48 * CA_LD];                 // 6240 B
    __shared__ __align__(16) _Float16 bt[256 * 64];     // 32768 B
    int tid = threadIdx.x;
    // stage comps1 (zero-padded 48x64)
    for (int q = tid; q < 48 * 64; q += 256) {
        int row = q >> 6, k = q & 63;
        float v = (row < R_TOT && k < NB) ? comps1[row * NB + k] : 0.f;
        ca[row * CA_LD + k] = (_Float16)v;
    }
    // stage bases1 tile: 40 k-rows x 256 cols; coalesced float2 loads
    int cb = blockIdx.x * 256;
#pragma unroll
    for (int i = 0; i < 20; i++) {
        int q = i * 256 + tid;          // 0..5119
        int k = q >> 7;                  // 0..39
        int c2 = q & 127;                // float2 index within row
        float2 v = *(const float2*)(bases1 + (size_t)k * NE_COL + cb + 2 * c2);
        int kb = k >> 3, ko = k & 7;
        int swz = ((kb ^ (c2 & 7)) << 3) + ko;   // (col>>1)&7 == c2&7 for both cols
        bt[(2 * c2) * 64 + swz]     = (_Float16)v.x;
        bt[(2 * c2 + 1) * 64 + swz] = (_Float16)v.y;
    }
    __syncthreads();

    int lane = tid & 63, wave = tid >> 6;
    int c0 = lane & 15;          // col-sub (t) / A-row (r)
    int g  = lane >> 4;          // k-group
    // A fragments: [m-tile 0..2][k-chunk 0..1] -> rows m*16+c0, k = q*32+g*8+j
    f16x8 af[3][2];
#pragma unroll
    for (int m = 0; m < 3; m++)
#pragma unroll
        for (int q = 0; q < 2; q++)
#pragma unroll
            for (int j = 0; j < 8; j++)
                af[m][q][j] = ca[(m * 16 + c0) * CA_LD + q * 32 + g * 8 + j];

#pragma unroll 1
    for (int it = 0; it < 4; it++) {
        int lcol = wave * 64 + it * 16 + c0;   // 0..255
        int col  = cb + lcol;
        int hash = (lcol >> 1) & 7;
        const _Float16* bp = &bt[lcol * 64];
        f16x8 b0 = *(const f16x8*)(bp + ((g ^ hash) << 3));     // k = g*8+j
        f16x8 b1;
#pragma unroll
        for (int j = 0; j < 8; j++) b1[j] = (_Float16)0.f;
        if (g == 0) b1 = *(const f16x8*)(bp + ((4 ^ hash) << 3)); // k = 32+j
        f32x4 d0 = {0.f, 0.f, 0.f, 0.f};
        f32x4 d1 = {0.f, 0.f, 0.f, 0.f};
        f32x4 d2 = {0.f, 0.f, 0.f, 0.f};
        d0 = __builtin_amdgcn_mfma_f32_16x16x32_f16(af[0][0], b0, d0, 0, 0, 0);
        d0 = __builtin_amdgcn_mfma_f32_16x16x32_f16(af[0][1], b1, d0, 0, 0, 0);
        d1 = __builtin_amdgcn_mfma_f32_16x16x32_f16(af[1][0], b0, d1, 0, 0, 0);
        d1 = __builtin_amdgcn_mfma_f32_16x16x32_f16(af[1][1], b1, d1, 0, 0, 0);
        d2 = __builtin_amdgcn_mfma_f32_16x16x32_f16(af[2][0], b0, d2, 0, 0, 0);
        d2 = __builtin_amdgcn_mfma_f32_16x16x32_f16(af[2][1], b1, d2, 0, 0, 0);
#pragma unroll
        for (int i = 0; i < 4; i++) {                // rows 0..15
            int row = g * 4 + i;
            w1[(size_t)row * NE_COL + col] = f2bf(d0[i]);
        }
#pragma unroll
        for (int i = 0; i < 4; i++) {                // rows 16..31
            int row = 16 + g * 4 + i;
            w1[(size_t)row * NE_COL + col] = f2bf(d1[i]);
        }
#pragma unroll
        for (int i = 0; i < 4; i++) {                // rows 32..40 (predicated)
            int row = 32 + g * 4 + i;
            if (row < R_TOT)
                w1[(size_t)row * NE_COL + col] = f2bf(d2[i]);
        }
    }
}

// ---- K5: w2p[r,c,ep] = packed bf16 pair (e=2ep, 2ep+1) of ---------------------
//          sum_b comps2[r,b] * bases2[b,e,c]
__global__ void k_w2(const float* __restrict__ comps2, const float* __restrict__ bases2,
                     unsigned* __restrict__ w2p) {
    int r = blockIdx.x;        // 41 blocks
    int t = threadIdx.x;       // 128 = NCLS*EMB/2, t = c*8+ep
    int c = t >> 3, ep = t & 7;
    int e0 = 2 * ep, e1 = 2 * ep + 1;
    float a0 = 0.f, a1 = 0.f;
#pragma unroll 8
    for (int b = 0; b < NB; b++) {
        float cc = comps2[r * NB + b];
        a0 = fmaf(cc, bases2[b * (EMB * NCLS) + e0 * NCLS + c], a0);
        a1 = fmaf(cc, bases2[b * (EMB * NCLS) + e1 * NCLS + c], a1);
    }
    w2p[r * 128 + t] = ((unsigned)f2bf(a1) << 16) | (unsigned)f2bf(a0);
}

// ---- K6: layer-1 gather, 8 lanes/edge, 8-edge unroll ------------------------
__global__ void k_l1_gather(const int* __restrict__ off, const int2* __restrict__ recs,
                            const unsigned* __restrict__ w1p,
                            const float* __restrict__ bias1, float* __restrict__ h) {
    int t = blockIdx.x * blockDim.x + threadIdx.x;     // N_NODES*8
    if (t >= N_NODES * 8) return;
    int s = t >> 3, e2 = t & 7;
    int beg = off[s], end = off[s + 1];
    float ax = 0.f, ay = 0.f;
    int j = beg;
    for (; j + 7 < end; j += 8) {
        int2 rc[8];
        unsigned p[8];
#pragma unroll
        for (int k = 0; k < 8; k++) rc[k] = recs[j + k];
#pragma unroll
        for (int k = 0; k < 8; k++)
            p[k] = w1p[(size_t)(rc[k].x >> 16) * (NE_COL / 2) + (rc[k].x & 0xFFFF) * 8 + e2];
#pragma unroll
        for (int k = 0; k < 8; k++) {
            float v = __int_as_float(rc[k].y);
            ax = fmaf(v, __uint_as_float(p[k] << 16), ax);
            ay = fmaf(v, __uint_as_float(p[k] & 0xFFFF0000u), ay);
        }
    }
    for (; j < end; j++) {
        int2 rc = recs[j];
        unsigned p = w1p[(size_t)(rc.x >> 16) * (NE_COL / 2) + (rc.x & 0xFFFF) * 8 + e2];
        float v = __int_as_float(rc.y);
        ax = fmaf(v, __uint_as_float(p << 16), ax);
        ay = fmaf(v, __uint_as_float(p & 0xFFFF0000u), ay);
    }
    float2 res;
    res.x = fmaxf(ax + bias1[2 * e2], 0.f);
    res.y = fmaxf(ay + bias1[2 * e2 + 1], 0.f);
    ((float2*)h)[t] = res;
}

// ---- K6-alt (fallback if ws too small for w1): on-the-fly basis contraction -
__global__ void k_l1_gather_fly(const int* __restrict__ off, const int2* __restrict__ recs,
                                const float* __restrict__ comps1,
                                const float* __restrict__ bases1,
                                const float* __restrict__ bias1, float* __restrict__ h) {
    __shared__ float c1[R_TOT * NB];
    for (int q = threadIdx.x; q < R_TOT * NB; q += blockDim.x) c1[q] = comps1[q];
    __syncthreads();
    int t = blockIdx.x * blockDim.x + threadIdx.x;
    int s = t >> 4, e = t & 15;
    int beg = off[s], end = off[s + 1];
    float acc = 0.f;
    for (int j = beg; j < end; j++) {
        int2 rec = recs[j];
        int o = rec.x & 0xFFFF, r = rec.x >> 16;
        float v = __int_as_float(rec.y);
        const float* cr = &c1[r * NB];
        float w = 0.f;
#pragma unroll 8
        for (int b = 0; b < NB; b++) w += cr[b] * bases1[(size_t)b * NE_COL + o * EMB + e];
        acc += v * w;
    }
    h[t] = fmaxf(acc + bias1[e], 0.f);
}

// ---- K7: layer-2 gather, bf16 w2 in LDS -------------------------------------
// All 16 lanes of an edge-group load the same 64B h[o,:] row (L1 broadcast).
// w2 stored as packed bf16 pairs: [r][c][ep], c-stride 10 uints (lane-c bank
// pattern c*10%32 covers all 16 banks), r-stride 164 uints. 26,896 B LDS ->
// 4 blocks of 512 per CU (~100% occupancy vs 47% with the 53KB f32 tile).
#define W2C2 10
#define W2R2 (16 * W2C2 + 4)    // 164 uints per relation
__device__ __forceinline__ float l2_edge(int2 ra, const float* __restrict__ h,
                                         const unsigned* w2s, int cbase) {
    const float4* ha = (const float4*)(h + (size_t)(ra.x & 0xFFFF) * EMB);
    const unsigned* base = &w2s[(ra.x >> 16) * W2R2 + cbase];
    float4 h0 = ha[0], h1 = ha[1], h2 = ha[2], h3 = ha[3];
    uint2 q0 = *(const uint2*)(base + 0);
    uint2 q1 = *(const uint2*)(base + 2);
    uint2 q2 = *(const uint2*)(base + 4);
    uint2 q3 = *(const uint2*)(base + 6);
    float da;
    da  = h0.x * __uint_as_float(q0.x << 16);
    da = fmaf(h0.y, __uint_as_float(q0.x & 0xFFFF0000u), da);
    da = fmaf(h0.z, __uint_as_float(q0.y << 16), da);
    da = fmaf(h0.w, __uint_as_float(q0.y & 0xFFFF0000u), da);
    da = fmaf(h1.x, __uint_as_float(q1.x << 16), da);
    da = fmaf(h1.y, __uint_as_float(q1.x & 0xFFFF0000u), da);
    da = fmaf(h1.z, __uint_as_float(q1.y << 16), da);
    da = fmaf(h1.w, __uint_as_float(q1.y & 0xFFFF0000u), da);
    da = fmaf(h2.x, __uint_as_float(q2.x << 16), da);
    da = fmaf(h2.y, __uint_as_float(q2.x & 0xFFFF0000u), da);
    da = fmaf(h2.z, __uint_as_float(q2.y << 16), da);
    da = fmaf(h2.w, __uint_as_float(q2.y & 0xFFFF0000u), da);
    da = fmaf(h3.x, __uint_as_float(q3.x << 16), da);
    da = fmaf(h3.y, __uint_as_float(q3.x & 0xFFFF0000u), da);
    da = fmaf(h3.z, __uint_as_float(q3.y << 16), da);
    da = fmaf(h3.w, __uint_as_float(q3.y & 0xFFFF0000u), da);
    return __int_as_float(ra.y) * da;
}

__global__ void k_l2_gather(const int* __restrict__ off, const int2* __restrict__ recs,
                            const float* __restrict__ h, const unsigned* __restrict__ w2p,
                            const float* __restrict__ bias2, float* __restrict__ out) {
    __shared__ __align__(16) unsigned w2s[R_TOT * W2R2];   // 26,896 B
    for (int q = threadIdx.x; q < R_TOT * 128; q += blockDim.x) {
        int r = q >> 7;
        int x = q & 127;
        int c = x >> 3, ep = x & 7;
        w2s[r * W2R2 + c * W2C2 + ep] = w2p[q];
    }
    __syncthreads();
    int t = blockIdx.x * blockDim.x + threadIdx.x;
    if (t >= NE_COL) return;
    int s = t >> 4, c = t & 15;
    int beg = off[s], end = off[s + 1];
    int cbase = c * W2C2;
    float acc = 0.f;
    int j = beg;
    for (; j + 3 < end; j += 4) {
        int2 r0 = recs[j], r1 = recs[j + 1], r2 = recs[j + 2], r3 = recs[j + 3];
        float t0 = l2_edge(r0, h, w2s, cbase);
        float t1 = l2_edge(r1, h, w2s, cbase);
        float t2 = l2_edge(r2, h, w2s, cbase);
        float t3 = l2_edge(r3, h, w2s, cbase);
        acc += (t0 + t1) + (t2 + t3);
    }
    for (; j < end; j++) {
        acc += l2_edge(recs[j], h, w2s, cbase);
    }
    out[s * NCLS + c] = acc + bias2[c];
}

static inline size_t align64(size_t x) { return (x + 63) & ~(size_t)63; }

extern "C" void kernel_launch(void* const* d_in, const int* in_sizes, int n_in,
                              void* d_out, int out_size, void* d_ws, size_t ws_size,
                              hipStream_t stream) {
    const int*   src    = (const int*)d_in[0];
    const int*   dst    = (const int*)d_in[1];
    const int*   rel    = (const int*)d_in[2];
    const float* comps1 = (const float*)d_in[3];
    const float* bases1 = (const float*)d_in[4];
    const float* comps2 = (const float*)d_in[5];
    const float* bases2 = (const float*)d_in[6];
    const float* bias1  = (const float*)d_in[7];
    const float* bias2  = (const float*)d_in[8];
    float* out = (float*)d_out;
    (void)in_sizes; (void)n_in; (void)out_size;

    char* ws = (char*)d_ws;
    size_t off_b = 0;
    // w1 (bf16, 65.6 MB) first; cnt2 (16.4MB) + rank (4.2MB) alias its head
    // (both dead before k_w1 writes w1).
    unsigned short* w1 = (unsigned short*)ws;
    int2*  cnt2 = (int2*)ws;
    int*   rank = (int*)(ws + align64((size_t)R_TOT * N_NODES * 8));
    off_b = align64((size_t)R_TOT * NE_COL * 2);              // 65.6 MB
    int*      deg  = (int*)(ws + off_b);      off_b = align64(off_b + (size_t)N_NODES * 4);
    int*      off  = (int*)(ws + off_b);      off_b = align64(off_b + (size_t)(N_NODES + 1) * 4);
    int*      bsum = (int*)(ws + off_b);      off_b = align64(off_b + (size_t)256 * 4);
    int2*     recs = (int2*)(ws + off_b);     off_b = align64(off_b + (size_t)E_TOT * 8);
    float*    h    = (float*)(ws + off_b);    off_b = align64(off_b + (size_t)NE_COL * 4);
    unsigned* w2p  = (unsigned*)(ws + off_b); off_b = align64(off_b + (size_t)R_TOT * 128 * 4);
    const bool materialize_w1 = (ws_size >= off_b);
    if (!materialize_w1) {
        off_b = 0;
        cnt2 = (int2*)(ws + off_b);     off_b = align64(off_b + (size_t)R_TOT * N_NODES * 8);
        rank = (int*)(ws + off_b);      off_b = align64(off_b + (size_t)E_TOT * 4);
        deg  = (int*)(ws + off_b);      off_b = align64(off_b + (size_t)N_NODES * 4);
        off  = (int*)(ws + off_b);      off_b = align64(off_b + (size_t)(N_NODES + 1) * 4);
        bsum = (int*)(ws + off_b);      off_b = align64(off_b + (size_t)256 * 4);
        recs = (int2*)(ws + off_b);     off_b = align64(off_b + (size_t)E_TOT * 8);
        h    = (float*)(ws + off_b);    off_b = align64(off_b + (size_t)NE_COL * 4);
        w2p  = (unsigned*)(ws + off_b); off_b = align64(off_b + (size_t)R_TOT * 128 * 4);
    }

    // zero counts (.x of cnt2; .y overwritten by k_degA)
    hipMemsetAsync(cnt2, 0, (size_t)R_TOT * N_NODES * 8, stream);

    const int BLK = 256;
    const int g_edge = (E_TOT + BLK - 1) / BLK;           // 4102
    const int g_w1   = NE_COL / 256;                      // 3125 (exact)
    const int g_l1   = (N_NODES * 8 + BLK - 1) / BLK;     // 1563
    const int g_l1f  = (N_NODES * 16) / BLK;              // 3125 (fallback, 16-lane)
    const int g_l2   = (NE_COL + 511) / 512;              // 1563

    k_count<<<g_edge, BLK, 0, stream>>>(src, dst, rel, cnt2, rank);
    k_degA<<<NBLK_N, 256, 0, stream>>>(cnt2, deg, bsum);
    k_degB<<<1, 256, 0, stream>>>(bsum);
    k_degC<<<NBLK_N, 256, 0, stream>>>(deg, bsum, off);
    k_fill<<<g_edge, BLK, 0, stream>>>(src, dst, rel, cnt2, rank, off, recs);
    k_w2<<<R_TOT, 128, 0, stream>>>(comps2, bases2, w2p);

    if (materialize_w1) {
        k_w1<<<g_w1, 256, 0, stream>>>(comps1, bases1, w1);  // overwrites cnt2/rank (dead)
        k_l1_gather<<<g_l1, BLK, 0, stream>>>(off, recs, (const unsigned*)w1, bias1, h);
    } else {
        k_l1_gather_fly<<<g_l1f, BLK, 0, stream>>>(off, recs, comps1, bases1, bias1, h);
    }

    k_l2_gather<<<g_l2, 512, 0, stream>>>(off, recs, h, w2p, bias2, out);
}